// Round 1
// baseline (909.827 us; speedup 1.0000x reference)
//
#include <hip/hip_runtime.h>
#include <math.h>

#define NRAYS 8192
#define H1S 136   // padded stride for 128-wide activation rows (8*136 floats)

__device__ __forceinline__ float sigm(float x){ return 1.0f/(1.0f + __expf(-x)); }

__launch_bounds__(128, 2)
__global__ void neus_render_kernel(
    const float* __restrict__ rays_o, const float* __restrict__ rays_d,
    const float* __restrict__ W1, const float* __restrict__ b1,
    const float* __restrict__ W2, const float* __restrict__ b2,
    const float* __restrict__ W3, const float* __restrict__ b3,
    const float* __restrict__ R1, const float* __restrict__ r1,
    const float* __restrict__ R2, const float* __restrict__ r2,
    const float* __restrict__ s_val, float* __restrict__ out)
{
  __shared__ __align__(16) float h1buf[8*H1S];
  __shared__ float sD[128], sS[128], sD2[128], sS2[128];
  __shared__ float aw[128], cp[128], cs[128], cdfb[128];
  __shared__ float cf[128], dm[128], vw[128];
  __shared__ float fD[16], fS[16];
  __shared__ float red[128];
  __shared__ float red3[128*3];
  __shared__ float wr0[128], wr1[128], wr2[128];
  __shared__ float sR2[384];
  __shared__ float scr;
  __shared__ float redw[2][5];

  const int ray = blockIdx.x;
  const int t = threadIdx.x;
  const int j = t;

  // --- per-ray data (uniform loads, cached) ---
  float ro0 = rays_o[ray*3+0], ro1 = rays_o[ray*3+1], ro2 = rays_o[ray*3+2];
  float rx  = rays_d[ray*3+0], ry  = rays_d[ray*3+1], rz  = rays_d[ray*3+2];
  float nrm = sqrtf(rx*rx + ry*ry + rz*rz);
  float rd0 = rx/nrm, rd1 = ry/nrm, rd2 = rz/nrm;

  // --- weights: thread j owns neuron j ---
  float w1c0 = W1[j], w1c1 = W1[128+j], w1c2 = W1[256+j];
  float b1j = b1[j], b2j = b2[j], w3j = W3[j];
  float b3v = b3[0];
  float rc0 = R1[j],     rc1 = R1[128+j], rc2 = R1[256+j];
  float rc3 = R1[384+j], rc4 = R1[512+j], rc5 = R1[640+j];
  float r1j = r1[j];
  float r2b0 = r2[0], r2b1 = r2[1], r2b2 = r2[2];
  float sfin = s_val[0] * 64.0f;

  float w2c[128];
  #pragma unroll
  for (int k=0;k<128;k++) w2c[k] = W2[k*128+j];   // column j of W2

  sR2[j] = R2[j]; sR2[128+j] = R2[128+j]; sR2[256+j] = R2[256+j];

  // --- initial d: linspace(near, far, 64) ---
  if (t < 64){
    float tt = (float)t / 63.0f;
    sD[t] = 0.5f*(1.0f-tt) + 4.0f*tt;
  }
  __syncthreads();

  // --- SDF MLP eval for a chunk of 8 points; d from dsrc[dbase..], sdf to dst[dstbase..] ---
  auto eval_chunk = [&](const float* dsrc, int dbase, float* dst, int dstbase){
    #pragma unroll
    for (int p=0;p<8;p++){
      float dv = dsrc[dbase+p];
      float px = fmaf(dv, rd0, ro0);
      float py = fmaf(dv, rd1, ro1);
      float pz = fmaf(dv, rd2, ro2);
      float h = b1j;
      h = fmaf(px, w1c0, h); h = fmaf(py, w1c1, h); h = fmaf(pz, w1c2, h);
      h1buf[p*H1S + j] = fmaxf(h, 0.0f);
    }
    __syncthreads();
    float acc[8];
    #pragma unroll
    for (int p=0;p<8;p++) acc[p] = b2j;
    #pragma unroll
    for (int k4=0;k4<32;k4++){
      #pragma unroll
      for (int p=0;p<8;p++){
        const float4 hv = *(const float4*)&h1buf[p*H1S + 4*k4];
        acc[p] = fmaf(hv.x, w2c[4*k4+0], acc[p]);
        acc[p] = fmaf(hv.y, w2c[4*k4+1], acc[p]);
        acc[p] = fmaf(hv.z, w2c[4*k4+2], acc[p]);
        acc[p] = fmaf(hv.w, w2c[4*k4+3], acc[p]);
      }
    }
    __syncthreads();
    #pragma unroll
    for (int p=0;p<8;p++) h1buf[p*H1S + j] = fmaxf(acc[p],0.0f)*w3j;
    __syncthreads();
    {
      int p = t>>4, l = t&15;
      float s2 = 0.0f;
      #pragma unroll
      for (int m=0;m<8;m++) s2 += h1buf[p*H1S + l + 16*m];
      red[p*16+l] = s2;
    }
    __syncthreads();
    if (t < 8){
      float s3 = b3v;
      #pragma unroll
      for (int l2=0;l2<16;l2++) s3 += red[t*16+l2];
      dst[dstbase+t] = s3;
    }
    __syncthreads();
  };

  // Kogge-Stone wave scans + cross-wave combine
  auto scan_mul_excl = [&](int m)->float {
    float x = (t<m) ? (1.0f - aw[t] + 1e-10f) : 1.0f;
    #pragma unroll
    for (int off=1; off<64; off<<=1){
      float y = __shfl_up(x, off, 64);
      if ((t & 63) >= off) x *= y;
    }
    if (t == 63) scr = x;
    __syncthreads();
    if (t >= 64) x *= scr;
    cp[t] = x;
    __syncthreads();
    return (t==0) ? 1.0f : cp[t-1];   // exclusive cumprod
  };
  auto scan_add_incl = [&](float v)->float {
    float x = v;
    #pragma unroll
    for (int off=1; off<64; off<<=1){
      float y = __shfl_up(x, off, 64);
      if ((t & 63) >= off) x += y;
    }
    if (t == 63) scr = x;
    __syncthreads();
    if (t >= 64) x += scr;
    return x;
  };

  // --- initial SDF at 64 samples ---
  for (int c=0;c<8;c++) eval_chunk(sD, c*8, sS, c*8);

  // --- 4 upsampling iterations ---
  for (int it=0; it<4; it++){
    const int n = 64 + 16*it;
    const int m = n-1;
    const float s_i = 64.0f * (float)(1<<it);
    if (t < m){
      float d0 = sD[t], d1 = sD[t+1];
      float f0 = sS[t], f1 = sS[t+1];
      float mid = 0.5f*(f0+f1);
      float dv = (f1-f0)/(d1-d0+1e-5f);
      float pdv = 0.0f;
      if (t > 0) pdv = (f0 - sS[t-1])/(d0 - sD[t-1]+1e-5f);
      float dc = fminf(pdv, dv);
      dc = fminf(fmaxf(dc,-10.0f), 0.0f);
      float dist = d1-d0;
      float pe = mid - dc*dist*0.5f;
      float ne = mid + dc*dist*0.5f;
      float pc = sigm(pe*s_i);
      float nc = sigm(ne*s_i);
      aw[t] = (pc - nc + 1e-5f)/(pc + 1e-5f);   // alpha in (0,1]
    }
    __syncthreads();
    float T = scan_mul_excl(m);
    float wp = (t<m) ? (aw[t]*T + 1e-5f) : 0.0f;   // weights + 1e-5
    float ci = scan_add_incl(wp);
    cs[t] = ci;
    __syncthreads();
    float S = cs[m-1];
    if (t == 0) cdfb[0] = 0.0f;
    if (t < m) cdfb[t+1] = cs[t]/S;
    __syncthreads();
    if (t < 16){
      float u = (float)t / 15.0f;
      int ind = 0;
      for (int i=0;i<n;i++) ind += (cdfb[i] <= u) ? 1 : 0;  // searchsorted right (cdf sorted)
      int below = ind-1; if (below < 0) below = 0; if (below > n-1) below = n-1;
      int above = ind;   if (above > n-1) above = n-1;
      float cb = cdfb[below], ca = cdfb[above];
      float bb = sD[below],   ba = sD[above];
      float den = ca - cb;
      if (den < 1e-5f) den = 1.0f;
      float tt = (u - cb)/den;
      fD[t] = bb + tt*(ba-bb);
    }
    __syncthreads();
    for (int cc=0; cc<2; cc++) eval_chunk(fD, cc*8, fS, cc*8);
    // stable merge (old before fine on ties, matching stable argsort)
    if (t < n){
      float v = sD[t];
      int r = t;
      #pragma unroll
      for (int q=0;q<16;q++) r += (fD[q] < v) ? 1 : 0;
      sD2[r] = v; sS2[r] = sS[t];
    } else if (t < n+16){
      int q = t - n;
      float v = fD[q];
      int r = q;
      for (int i=0;i<n;i++) r += (sD[i] <= v) ? 1 : 0;
      sD2[r] = v; sS2[r] = fS[q];
    }
    __syncthreads();
    if (t < n+16){ sD[t] = sD2[t]; sS[t] = sS2[t]; }
    __syncthreads();
  }

  // --- final compositing (sdf_final == carried sS: same deterministic eval) ---
  cf[t] = sigm(sS[t]*sfin);
  __syncthreads();
  if (t < 127){
    float a = (cf[t]-cf[t+1]+1e-5f)/(cf[t]+1e-5f);
    a = fminf(fmaxf(a,0.0f),1.0f);
    aw[t] = a;
    dm[t] = 0.5f*(sD[t]+sD[t+1]);
  }
  __syncthreads();
  {
    float T = scan_mul_excl(127);
    if (t < 127) vw[t] = aw[t]*T;
  }
  __syncthreads();

  // --- radiance net at 127 midpoints, 16 chunks of 8 ---
  for (int c=0;c<16;c++){
    const int base = c*8;
    #pragma unroll
    for (int p=0;p<8;p++){
      int idx = base+p;
      float h = 0.0f;
      if (idx < 127){
        float dmv = dm[idx];
        float px = fmaf(dmv, rd0, ro0);
        float py = fmaf(dmv, rd1, ro1);
        float pz = fmaf(dmv, rd2, ro2);
        h = r1j;
        h = fmaf(px, rc0, h); h = fmaf(py, rc1, h); h = fmaf(pz, rc2, h);
        h = fmaf(rd0, rc3, h); h = fmaf(rd1, rc4, h); h = fmaf(rd2, rc5, h);
        h = fmaxf(h, 0.0f);
      }
      h1buf[p*H1S + j] = h;
    }
    __syncthreads();
    {
      int p = t>>4, l = t&15;
      float a0=0.f,a1=0.f,a2=0.f;
      #pragma unroll
      for (int mm=0;mm<8;mm++){
        int k = l + 16*mm;
        float h = h1buf[p*H1S + k];
        a0 = fmaf(h, sR2[k*3+0], a0);
        a1 = fmaf(h, sR2[k*3+1], a1);
        a2 = fmaf(h, sR2[k*3+2], a2);
      }
      red3[t*3+0]=a0; red3[t*3+1]=a1; red3[t*3+2]=a2;
    }
    __syncthreads();
    if (t < 8){
      int idx = base + t;
      if (idx < 127){
        float s0=r2b0, s1=r2b1, s2v=r2b2;
        #pragma unroll
        for (int l2=0;l2<16;l2++){
          s0  += red3[(t*16+l2)*3+0];
          s1  += red3[(t*16+l2)*3+1];
          s2v += red3[(t*16+l2)*3+2];
        }
        float wgt = vw[idx];
        wr0[idx] = wgt * sigm(s0);
        wr1[idx] = wgt * sigm(s1);
        wr2[idx] = wgt * sigm(s2v);
      }
    }
    __syncthreads();
  }

  // --- final reductions: rgb(3), depth, acc ---
  float v0 = (t<127)? wr0[t] : 0.f;
  float v1 = (t<127)? wr1[t] : 0.f;
  float v2 = (t<127)? wr2[t] : 0.f;
  float v3 = (t<127)? vw[t]*dm[t] : 0.f;
  float v4 = (t<127)? vw[t] : 0.f;
  #pragma unroll
  for (int off=32; off>=1; off>>=1){
    v0 += __shfl_xor(v0, off, 64);
    v1 += __shfl_xor(v1, off, 64);
    v2 += __shfl_xor(v2, off, 64);
    v3 += __shfl_xor(v3, off, 64);
    v4 += __shfl_xor(v4, off, 64);
  }
  if ((t&63)==0){
    int wv = t>>6;
    redw[wv][0]=v0; redw[wv][1]=v1; redw[wv][2]=v2; redw[wv][3]=v3; redw[wv][4]=v4;
  }
  __syncthreads();
  if (t==0){
    out[ray*5+0] = redw[0][0]+redw[1][0];
    out[ray*5+1] = redw[0][1]+redw[1][1];
    out[ray*5+2] = redw[0][2]+redw[1][2];
    out[ray*5+3] = redw[0][3]+redw[1][3];
    out[ray*5+4] = redw[0][4]+redw[1][4];
  }
}

extern "C" void kernel_launch(void* const* d_in, const int* in_sizes, int n_in,
                              void* d_out, int out_size, void* d_ws, size_t ws_size,
                              hipStream_t stream) {
  const float* rays_o = (const float*)d_in[0];
  const float* rays_d = (const float*)d_in[1];
  const float* W1 = (const float*)d_in[2];
  const float* b1 = (const float*)d_in[3];
  const float* W2 = (const float*)d_in[4];
  const float* b2 = (const float*)d_in[5];
  const float* W3 = (const float*)d_in[6];
  const float* b3 = (const float*)d_in[7];
  const float* R1 = (const float*)d_in[8];
  const float* r1 = (const float*)d_in[9];
  const float* R2 = (const float*)d_in[10];
  const float* r2 = (const float*)d_in[11];
  const float* sv = (const float*)d_in[12];
  float* out = (float*)d_out;
  neus_render_kernel<<<NRAYS, 128, 0, stream>>>(
      rays_o, rays_d, W1, b1, W2, b2, W3, b3, R1, r1, R2, r2, sv, out);
}

// Round 2
// 429.693 us; speedup vs baseline: 2.1174x; 2.1174x over previous
//
#include <hip/hip_runtime.h>
#include <math.h>

#define NRAYS 8192
#define H1S 136   // padded stride for radiance h1 rows (fp32)
#define AS  136   // padded stride (in f16 elems) for A-operand rows

typedef _Float16 half8 __attribute__((ext_vector_type(8)));
typedef float floatx4 __attribute__((ext_vector_type(4)));

__device__ __forceinline__ float sigm(float x){ return 1.0f/(1.0f + __expf(-x)); }

__launch_bounds__(128, 2)
__global__ void neus_render_kernel(
    const float* __restrict__ rays_o, const float* __restrict__ rays_d,
    const float* __restrict__ W1, const float* __restrict__ b1,
    const float* __restrict__ W2, const float* __restrict__ b2,
    const float* __restrict__ W3, const float* __restrict__ b3,
    const float* __restrict__ R1, const float* __restrict__ r1,
    const float* __restrict__ R2, const float* __restrict__ r2,
    const float* __restrict__ s_val, float* __restrict__ out)
{
  __shared__ __align__(16) _Float16 Ahi[16*AS];
  __shared__ __align__(16) _Float16 Alo[16*AS];
  __shared__ __align__(16) float h1buf[8*H1S];
  __shared__ float sD[128], sS[128], sD2[128], sS2[128];
  __shared__ float aw[128], cp[128], cs[128], cdfb[128];
  __shared__ float cf[128], dm[128], vw[128];
  __shared__ float fD[16], fS[16];
  __shared__ float red[128];
  __shared__ float red3[128*3];
  __shared__ float wr0[128], wr1[128], wr2[128];
  __shared__ float sR2[384];
  __shared__ float pw[2][16];
  __shared__ int   cntw[2][16];
  __shared__ float scr;
  __shared__ float redw[2][5];

  const int ray = blockIdx.x;
  const int t = threadIdx.x;
  const int j = t;

  // --- per-ray data ---
  float ro0 = rays_o[ray*3+0], ro1 = rays_o[ray*3+1], ro2 = rays_o[ray*3+2];
  float rx  = rays_d[ray*3+0], ry  = rays_d[ray*3+1], rz  = rays_d[ray*3+2];
  float nrm = sqrtf(rx*rx + ry*ry + rz*rz);
  float rd0 = rx/nrm, rd1 = ry/nrm, rd2 = rz/nrm;

  // --- layer-1 weights: thread j owns neuron j ---
  float w1c0 = W1[j], w1c1 = W1[128+j], w1c2 = W1[256+j];
  float b1j = b1[j];
  float b3v = b3[0];
  float rc0 = R1[j],     rc1 = R1[128+j], rc2 = R1[256+j];
  float rc3 = R1[384+j], rc4 = R1[512+j], rc5 = R1[640+j];
  float r1j = r1[j];
  float r2b0 = r2[0], r2b1 = r2[1], r2b2 = r2[2];
  float sfin = s_val[0] * 64.0f;

  // --- MFMA B-fragments for W2 (f16, resident in regs/AGPRs) ---
  // wave w covers neurons n in [w*64, w*64+64): 4 ntiles of 16.
  // lane: n = w*64 + i*16 + (t&15); k = kt*32 + q*8 + jj, q=(t>>4)&3.
  const int wv_ = t>>6, l15 = t&15, q4 = (t>>4)&3;
  half8 Bf[16];
  float b2v[4], w3v[4];
  #pragma unroll
  for (int i=0;i<4;i++){
    int n = wv_*64 + i*16 + l15;
    b2v[i] = b2[n];
    w3v[i] = W3[n];
    #pragma unroll
    for (int kt=0;kt<4;kt++){
      int k0 = kt*32 + q4*8;
      half8 bf;
      #pragma unroll
      for (int jj=0;jj<8;jj++) bf[jj] = (_Float16)W2[(k0+jj)*128 + n];
      Bf[i*4+kt] = bf;
    }
  }

  sR2[j] = R2[j]; sR2[128+j] = R2[128+j]; sR2[256+j] = R2[256+j];

  // --- initial d: linspace(near, far, 64) ---
  if (t < 64){
    float tt = (float)t / 63.0f;
    sD[t] = 0.5f*(1.0f-tt) + 4.0f*tt;
  }
  __syncthreads();

  // --- SDF MLP eval for 16 points via MFMA (fp16 hi/lo split A, fp16 B) ---
  auto eval16 = [&](const float* dsrc, int dbase, float* dst, int dstbase){
    // layer 1 (VALU): thread t owns neuron t, loops 16 points
    #pragma unroll
    for (int m=0;m<16;m++){
      float dv = dsrc[dbase+m];
      float px = fmaf(dv, rd0, ro0);
      float py = fmaf(dv, rd1, ro1);
      float pz = fmaf(dv, rd2, ro2);
      float h = b1j;
      h = fmaf(px, w1c0, h); h = fmaf(py, w1c1, h); h = fmaf(pz, w1c2, h);
      h = fmaxf(h, 0.0f);
      _Float16 hh = (_Float16)h;
      _Float16 hl = (_Float16)(h - (float)hh);
      Ahi[m*AS + t] = hh;
      Alo[m*AS + t] = hl;
    }
    __syncthreads();
    // A-fragments: lane reads A[m=lane&15][kt*32 + q*8 .. +8]
    half8 ah[4], al[4];
    const int mrow = t&15;
    #pragma unroll
    for (int kt=0;kt<4;kt++){
      ah[kt] = *(const half8*)&Ahi[mrow*AS + kt*32 + q4*8];
      al[kt] = *(const half8*)&Alo[mrow*AS + kt*32 + q4*8];
    }
    floatx4 acc[4];
    #pragma unroll
    for (int i=0;i<4;i++) acc[i] = (floatx4){0.f,0.f,0.f,0.f};
    #pragma unroll
    for (int i=0;i<4;i++){
      #pragma unroll
      for (int kt=0;kt<4;kt++){
        acc[i] = __builtin_amdgcn_mfma_f32_16x16x32_f16(ah[kt], Bf[i*4+kt], acc[i], 0,0,0);
        acc[i] = __builtin_amdgcn_mfma_f32_16x16x32_f16(al[kt], Bf[i*4+kt], acc[i], 0,0,0);
      }
    }
    // epilogue: relu(h2 + b2)*w3, reduce over n
    float part[4] = {0.f,0.f,0.f,0.f};
    #pragma unroll
    for (int i=0;i<4;i++){
      #pragma unroll
      for (int r=0;r<4;r++){
        part[r] += fmaxf(acc[i][r] + b2v[i], 0.0f) * w3v[i];
      }
    }
    #pragma unroll
    for (int off=1; off<16; off<<=1){
      #pragma unroll
      for (int r=0;r<4;r++) part[r] += __shfl_xor(part[r], off, 64);
    }
    if ((t&15)==0){
      #pragma unroll
      for (int r=0;r<4;r++) pw[wv_][q4*4+r] = part[r];
    }
    __syncthreads();
    if (t<16) dst[dstbase+t] = pw[0][t] + pw[1][t] + b3v;
    __syncthreads();
  };

  // Kogge-Stone wave scans + cross-wave combine
  auto scan_mul_excl = [&](int m)->float {
    float x = (t<m) ? (1.0f - aw[t] + 1e-10f) : 1.0f;
    #pragma unroll
    for (int off=1; off<64; off<<=1){
      float y = __shfl_up(x, off, 64);
      if ((t & 63) >= off) x *= y;
    }
    if (t == 63) scr = x;
    __syncthreads();
    if (t >= 64) x *= scr;
    cp[t] = x;
    __syncthreads();
    return (t==0) ? 1.0f : cp[t-1];
  };
  auto scan_add_incl = [&](float v)->float {
    float x = v;
    #pragma unroll
    for (int off=1; off<64; off<<=1){
      float y = __shfl_up(x, off, 64);
      if ((t & 63) >= off) x += y;
    }
    if (t == 63) scr = x;
    __syncthreads();
    if (t >= 64) x += scr;
    return x;
  };

  // --- initial SDF at 64 samples ---
  for (int c=0;c<4;c++) eval16(sD, c*16, sS, c*16);

  // --- 4 upsampling iterations ---
  for (int it=0; it<4; it++){
    const int n = 64 + 16*it;
    const int m = n-1;
    const float s_i = 64.0f * (float)(1<<it);
    if (t < m){
      float d0 = sD[t], d1 = sD[t+1];
      float f0 = sS[t], f1 = sS[t+1];
      float mid = 0.5f*(f0+f1);
      float dv = (f1-f0)/(d1-d0+1e-5f);
      float pdv = 0.0f;
      if (t > 0) pdv = (f0 - sS[t-1])/(d0 - sD[t-1]+1e-5f);
      float dc = fminf(pdv, dv);
      dc = fminf(fmaxf(dc,-10.0f), 0.0f);
      float dist = d1-d0;
      float pe = mid - dc*dist*0.5f;
      float ne = mid + dc*dist*0.5f;
      float pc = sigm(pe*s_i);
      float nc = sigm(ne*s_i);
      aw[t] = (pc - nc + 1e-5f)/(pc + 1e-5f);
    }
    __syncthreads();
    float T = scan_mul_excl(m);
    float wp = (t<m) ? (aw[t]*T + 1e-5f) : 0.0f;
    float ci = scan_add_incl(wp);
    cs[t] = ci;
    __syncthreads();
    float S = cs[m-1];
    if (t == 0) cdfb[0] = 0.0f;
    if (t < m) cdfb[t+1] = cs[t]/S;
    __syncthreads();
    // searchsorted-right via ballot: ind(u) = #{i<n : cdfb[i] <= u}
    {
      float cv = (t < n) ? cdfb[t] : 2.0f;
      #pragma unroll
      for (int q2=0;q2<16;q2++){
        float uq = (float)q2 / 15.0f;
        unsigned long long mk = __ballot(cv <= uq);
        if ((t&63)==0) cntw[t>>6][q2] = __popcll(mk);
      }
    }
    __syncthreads();
    if (t < 16){
      float u = (float)t / 15.0f;
      int ind = cntw[0][t] + cntw[1][t];
      int below = ind-1; if (below < 0) below = 0; if (below > n-1) below = n-1;
      int above = ind;   if (above > n-1) above = n-1;
      float cb = cdfb[below], ca = cdfb[above];
      float bb = sD[below],   ba = sD[above];
      float den = ca - cb;
      if (den < 1e-5f) den = 1.0f;
      float tt = (u - cb)/den;
      fD[t] = bb + tt*(ba-bb);
    }
    __syncthreads();
    eval16(fD, 0, fS, 0);
    // stable merge of sorted old (ties-first) with sorted fine
    {
      float dval = (t<n) ? sD[t] : 3.0e38f;
      int rold = t;
      #pragma unroll
      for (int q2=0;q2<16;q2++){
        float fq = fD[q2];
        unsigned long long mk = __ballot(dval <= fq);  // #{old <= fq}
        if ((t&63)==0) cntw[t>>6][q2] = __popcll(mk);
        rold += (fq < dval) ? 1 : 0;
      }
      __syncthreads();
      if (t < n){ sD2[rold] = dval; sS2[rold] = sS[t]; }
      if (t < 16){
        int rf = t + cntw[0][t] + cntw[1][t];
        sD2[rf] = fD[t]; sS2[rf] = fS[t];
      }
    }
    __syncthreads();
    if (t < n+16){ sD[t] = sD2[t]; sS[t] = sS2[t]; }
    __syncthreads();
  }

  // --- final compositing (sdf_final == carried sS) ---
  cf[t] = sigm(sS[t]*sfin);
  __syncthreads();
  if (t < 127){
    float a = (cf[t]-cf[t+1]+1e-5f)/(cf[t]+1e-5f);
    a = fminf(fmaxf(a,0.0f),1.0f);
    aw[t] = a;
    dm[t] = 0.5f*(sD[t]+sD[t+1]);
  }
  __syncthreads();
  {
    float T = scan_mul_excl(127);
    if (t < 127) vw[t] = aw[t]*T;
  }
  __syncthreads();

  // --- radiance net at 127 midpoints, 16 chunks of 8 ---
  for (int c=0;c<16;c++){
    const int base = c*8;
    #pragma unroll
    for (int p=0;p<8;p++){
      int idx = base+p;
      float h = 0.0f;
      if (idx < 127){
        float dmv = dm[idx];
        float px = fmaf(dmv, rd0, ro0);
        float py = fmaf(dmv, rd1, ro1);
        float pz = fmaf(dmv, rd2, ro2);
        h = r1j;
        h = fmaf(px, rc0, h); h = fmaf(py, rc1, h); h = fmaf(pz, rc2, h);
        h = fmaf(rd0, rc3, h); h = fmaf(rd1, rc4, h); h = fmaf(rd2, rc5, h);
        h = fmaxf(h, 0.0f);
      }
      h1buf[p*H1S + j] = h;
    }
    __syncthreads();
    {
      int p = t>>4, l = t&15;
      float a0=0.f,a1=0.f,a2=0.f;
      #pragma unroll
      for (int mm=0;mm<8;mm++){
        int k = l + 16*mm;
        float h = h1buf[p*H1S + k];
        a0 = fmaf(h, sR2[k*3+0], a0);
        a1 = fmaf(h, sR2[k*3+1], a1);
        a2 = fmaf(h, sR2[k*3+2], a2);
      }
      red3[t*3+0]=a0; red3[t*3+1]=a1; red3[t*3+2]=a2;
    }
    __syncthreads();
    if (t < 8){
      int idx = base + t;
      if (idx < 127){
        float s0=r2b0, s1=r2b1, s2v=r2b2;
        #pragma unroll
        for (int l2=0;l2<16;l2++){
          s0  += red3[(t*16+l2)*3+0];
          s1  += red3[(t*16+l2)*3+1];
          s2v += red3[(t*16+l2)*3+2];
        }
        float wgt = vw[idx];
        wr0[idx] = wgt * sigm(s0);
        wr1[idx] = wgt * sigm(s1);
        wr2[idx] = wgt * sigm(s2v);
      }
    }
    __syncthreads();
  }

  // --- final reductions: rgb(3), depth, acc ---
  float v0 = (t<127)? wr0[t] : 0.f;
  float v1 = (t<127)? wr1[t] : 0.f;
  float v2 = (t<127)? wr2[t] : 0.f;
  float v3 = (t<127)? vw[t]*dm[t] : 0.f;
  float v4 = (t<127)? vw[t] : 0.f;
  #pragma unroll
  for (int off=32; off>=1; off>>=1){
    v0 += __shfl_xor(v0, off, 64);
    v1 += __shfl_xor(v1, off, 64);
    v2 += __shfl_xor(v2, off, 64);
    v3 += __shfl_xor(v3, off, 64);
    v4 += __shfl_xor(v4, off, 64);
  }
  if ((t&63)==0){
    int wv = t>>6;
    redw[wv][0]=v0; redw[wv][1]=v1; redw[wv][2]=v2; redw[wv][3]=v3; redw[wv][4]=v4;
  }
  __syncthreads();
  if (t==0){
    out[ray*5+0] = redw[0][0]+redw[1][0];
    out[ray*5+1] = redw[0][1]+redw[1][1];
    out[ray*5+2] = redw[0][2]+redw[1][2];
    out[ray*5+3] = redw[0][3]+redw[1][3];
    out[ray*5+4] = redw[0][4]+redw[1][4];
  }
}

extern "C" void kernel_launch(void* const* d_in, const int* in_sizes, int n_in,
                              void* d_out, int out_size, void* d_ws, size_t ws_size,
                              hipStream_t stream) {
  const float* rays_o = (const float*)d_in[0];
  const float* rays_d = (const float*)d_in[1];
  const float* W1 = (const float*)d_in[2];
  const float* b1 = (const float*)d_in[3];
  const float* W2 = (const float*)d_in[4];
  const float* b2 = (const float*)d_in[5];
  const float* W3 = (const float*)d_in[6];
  const float* b3 = (const float*)d_in[7];
  const float* R1 = (const float*)d_in[8];
  const float* r1 = (const float*)d_in[9];
  const float* R2 = (const float*)d_in[10];
  const float* r2 = (const float*)d_in[11];
  const float* sv = (const float*)d_in[12];
  float* out = (float*)d_out;
  neus_render_kernel<<<NRAYS, 128, 0, stream>>>(
      rays_o, rays_d, W1, b1, W2, b2, W3, b3, R1, r1, R2, r2, sv, out);
}

// Round 3
// 344.046 us; speedup vs baseline: 2.6445x; 1.2489x over previous
//
#include <hip/hip_runtime.h>
#include <math.h>

#define NRAYS 8192
#define AS  136   // padded stride (f16 elems) for A-operand rows

typedef _Float16 half8 __attribute__((ext_vector_type(8)));
typedef float floatx4 __attribute__((ext_vector_type(4)));

__device__ __forceinline__ float sigm(float x){ return 1.0f/(1.0f + __expf(-x)); }

__launch_bounds__(128, 2)
__global__ void neus_render_kernel(
    const float* __restrict__ rays_o, const float* __restrict__ rays_d,
    const float* __restrict__ W1, const float* __restrict__ b1,
    const float* __restrict__ W2, const float* __restrict__ b2,
    const float* __restrict__ W3, const float* __restrict__ b3,
    const float* __restrict__ R1, const float* __restrict__ r1,
    const float* __restrict__ R2, const float* __restrict__ r2,
    const float* __restrict__ s_val, float* __restrict__ out)
{
  __shared__ __align__(16) _Float16 Ah[32*AS];  // eval16: rows 0-15 hi, 16-31 lo; radiance: rows 0-31
  __shared__ __align__(16) float sD[128], sS[128], sD2[128], sS2[128];
  __shared__ float aw[128], cp[128], cs[128], cdfb[128];
  __shared__ float cf[128];
  __shared__ __align__(16) float dm[128], vw[128];
  __shared__ __align__(16) float fD[16], fS[16];
  __shared__ float pw[2][16];
  __shared__ int   cntw[2][16];
  __shared__ float scr;
  __shared__ float redw[2][2];
  __shared__ float rgbw[2][3];

  const int ray = blockIdx.x;
  const int t = threadIdx.x;
  const int wv_ = t>>6, l15 = t&15, q4 = (t>>4)&3;

  // --- per-ray data ---
  float ro0 = rays_o[ray*3+0], ro1 = rays_o[ray*3+1], ro2 = rays_o[ray*3+2];
  float rx  = rays_d[ray*3+0], ry  = rays_d[ray*3+1], rz  = rays_d[ray*3+2];
  float nrm = sqrtf(rx*rx + ry*ry + rz*rz);
  float rd0 = rx/nrm, rd1 = ry/nrm, rd2 = rz/nrm;

  // --- affine-collapsed layer-1 weights (thread t owns neuron t) ---
  float w1a = W1[t], w1b = W1[128+t], w1c = W1[256+t];
  float u1 = rd0*w1a + rd1*w1b + rd2*w1c;
  float v1 = ro0*w1a + ro1*w1b + ro2*w1c + b1[t];
  float b3v = b3[0];
  float ra = R1[t],     rb_ = R1[128+t], rc_ = R1[256+t];
  float rdw = R1[384+t], re = R1[512+t], rf = R1[640+t];
  float uR = rd0*ra + rd1*rb_ + rd2*rc_;
  float vR = ro0*ra + ro1*rb_ + ro2*rc_ + rd0*rdw + rd1*re + rd2*rf + r1[t];
  float sfin = s_val[0] * 64.0f;
  float r2lane = (l15==0) ? r2[0] : (l15==1) ? r2[1] : (l15==2) ? r2[2] : 0.0f;

  // --- MFMA B-fragments for W2 (f16, reg-resident): wave wv_ covers neurons [wv_*64, +64) ---
  half8 Bf[16];
  float b2v[4], w3v[4];
  #pragma unroll
  for (int i=0;i<4;i++){
    int n = wv_*64 + i*16 + l15;
    b2v[i] = b2[n];
    w3v[i] = W3[n];
    #pragma unroll
    for (int kt=0;kt<4;kt++){
      int k0 = kt*32 + q4*8;
      half8 bf;
      #pragma unroll
      for (int jj=0;jj<8;jj++) bf[jj] = (_Float16)W2[(k0+jj)*128 + n];
      Bf[i*4+kt] = bf;
    }
  }
  // --- MFMA B-fragment for R2 [128x3], cols padded to 16 ---
  half8 RBf[4];
  #pragma unroll
  for (int kt=0;kt<4;kt++){
    half8 bf;
    #pragma unroll
    for (int jj=0;jj<8;jj++){
      int k = kt*32 + q4*8 + jj;
      bf[jj] = (l15<3) ? (_Float16)R2[k*3 + l15] : (_Float16)0.0f;
    }
    RBf[kt] = bf;
  }

  // --- initial d: linspace(near, far, 64) ---
  if (t < 64){
    float tt = (float)t / 63.0f;
    sD[t] = 0.5f*(1.0f-tt) + 4.0f*tt;
  }
  __syncthreads();

  // --- SDF MLP eval for 16 points via MFMA (fp16 hi/lo split A, fp16 B) ---
  auto eval16 = [&](const float* dsrc, int dbase, float* dst, int dstbase){
    #pragma unroll
    for (int mq=0;mq<4;mq++){
      const float4 dv4 = *(const float4*)&dsrc[dbase+mq*4];
      const float dd[4] = {dv4.x, dv4.y, dv4.z, dv4.w};
      #pragma unroll
      for (int r=0;r<4;r++){
        int m = mq*4+r;
        float h = fmaxf(fmaf(dd[r], u1, v1), 0.0f);
        _Float16 hh = (_Float16)h;
        Ah[m*AS + t] = hh;
        Ah[(16+m)*AS + t] = (_Float16)(h - (float)hh);
      }
    }
    __syncthreads();
    half8 ah[4], al[4];
    #pragma unroll
    for (int kt=0;kt<4;kt++){
      ah[kt] = *(const half8*)&Ah[l15*AS      + kt*32 + q4*8];
      al[kt] = *(const half8*)&Ah[(16+l15)*AS + kt*32 + q4*8];
    }
    floatx4 acc[4];
    #pragma unroll
    for (int i=0;i<4;i++) acc[i] = (floatx4){0.f,0.f,0.f,0.f};
    #pragma unroll
    for (int i=0;i<4;i++){
      #pragma unroll
      for (int kt=0;kt<4;kt++){
        acc[i] = __builtin_amdgcn_mfma_f32_16x16x32_f16(ah[kt], Bf[i*4+kt], acc[i], 0,0,0);
        acc[i] = __builtin_amdgcn_mfma_f32_16x16x32_f16(al[kt], Bf[i*4+kt], acc[i], 0,0,0);
      }
    }
    float part[4] = {0.f,0.f,0.f,0.f};
    #pragma unroll
    for (int i=0;i<4;i++){
      #pragma unroll
      for (int r=0;r<4;r++)
        part[r] += fmaxf(acc[i][r] + b2v[i], 0.0f) * w3v[i];
    }
    #pragma unroll
    for (int off=1; off<16; off<<=1){
      #pragma unroll
      for (int r=0;r<4;r++) part[r] += __shfl_xor(part[r], off, 64);
    }
    if ((t&15)==0){
      #pragma unroll
      for (int r=0;r<4;r++) pw[wv_][q4*4+r] = part[r];
    }
    __syncthreads();
    if (t<16) dst[dstbase+t] = pw[0][t] + pw[1][t] + b3v;
    __syncthreads();
  };

  // Kogge-Stone wave scans + cross-wave combine
  auto scan_mul_excl = [&](int m)->float {
    float x = (t<m) ? (1.0f - aw[t] + 1e-10f) : 1.0f;
    #pragma unroll
    for (int off=1; off<64; off<<=1){
      float y = __shfl_up(x, off, 64);
      if ((t & 63) >= off) x *= y;
    }
    if (t == 63) scr = x;
    __syncthreads();
    if (t >= 64) x *= scr;
    cp[t] = x;
    __syncthreads();
    return (t==0) ? 1.0f : cp[t-1];
  };
  auto scan_add_incl = [&](float v)->float {
    float x = v;
    #pragma unroll
    for (int off=1; off<64; off<<=1){
      float y = __shfl_up(x, off, 64);
      if ((t & 63) >= off) x += y;
    }
    if (t == 63) scr = x;
    __syncthreads();
    if (t >= 64) x += scr;
    return x;
  };

  // --- initial SDF at 64 samples ---
  for (int c=0;c<4;c++) eval16(sD, c*16, sS, c*16);

  // --- 4 upsampling iterations ---
  for (int it=0; it<4; it++){
    const int n = 64 + 16*it;
    const int m = n-1;
    const float s_i = 64.0f * (float)(1<<it);
    if (t < m){
      float d0 = sD[t], d1 = sD[t+1];
      float f0 = sS[t], f1 = sS[t+1];
      float mid = 0.5f*(f0+f1);
      float dv = (f1-f0)/(d1-d0+1e-5f);
      float pdv = 0.0f;
      if (t > 0) pdv = (f0 - sS[t-1])/(d0 - sD[t-1]+1e-5f);
      float dc = fminf(pdv, dv);
      dc = fminf(fmaxf(dc,-10.0f), 0.0f);
      float dist = d1-d0;
      float pe = mid - dc*dist*0.5f;
      float ne = mid + dc*dist*0.5f;
      float pc = sigm(pe*s_i);
      float nc = sigm(ne*s_i);
      aw[t] = (pc - nc + 1e-5f)/(pc + 1e-5f);
    }
    __syncthreads();
    float T = scan_mul_excl(m);
    float wp = (t<m) ? (aw[t]*T + 1e-5f) : 0.0f;
    float ci = scan_add_incl(wp);
    cs[t] = ci;
    __syncthreads();
    float S = cs[m-1];
    if (t == 0) cdfb[0] = 0.0f;
    if (t < m) cdfb[t+1] = cs[t]/S;
    __syncthreads();
    // searchsorted-right via ballot
    {
      float cv = (t < n) ? cdfb[t] : 2.0f;
      #pragma unroll
      for (int q2=0;q2<16;q2++){
        float uq = (float)q2 / 15.0f;
        unsigned long long mk = __ballot(cv <= uq);
        if ((t&63)==0) cntw[t>>6][q2] = __popcll(mk);
      }
    }
    __syncthreads();
    if (t < 16){
      float u = (float)t / 15.0f;
      int ind = cntw[0][t] + cntw[1][t];
      int below = ind-1; if (below < 0) below = 0; if (below > n-1) below = n-1;
      int above = ind;   if (above > n-1) above = n-1;
      float cb = cdfb[below], ca = cdfb[above];
      float bb = sD[below],   ba = sD[above];
      float den = ca - cb;
      if (den < 1e-5f) den = 1.0f;
      float tt = (u - cb)/den;
      fD[t] = bb + tt*(ba-bb);
    }
    __syncthreads();
    eval16(fD, 0, fS, 0);
    // stable merge of sorted old (ties-first) with sorted fine
    {
      float dval = (t<n) ? sD[t] : 3.0e38f;
      int rold = t;
      #pragma unroll
      for (int q2=0;q2<16;q2++){
        float fq = fD[q2];
        unsigned long long mk = __ballot(dval <= fq);
        if ((t&63)==0) cntw[t>>6][q2] = __popcll(mk);
        rold += (fq < dval) ? 1 : 0;
      }
      __syncthreads();
      if (t < n){ sD2[rold] = dval; sS2[rold] = sS[t]; }
      if (t < 16){
        int rf2 = t + cntw[0][t] + cntw[1][t];
        sD2[rf2] = fD[t]; sS2[rf2] = fS[t];
      }
    }
    __syncthreads();
    if (t < n+16){ sD[t] = sD2[t]; sS[t] = sS2[t]; }
    __syncthreads();
  }

  // --- final compositing (sdf_final == carried sS) ---
  cf[t] = sigm(sS[t]*sfin);
  __syncthreads();
  if (t < 127){
    float a = (cf[t]-cf[t+1]+1e-5f)/(cf[t]+1e-5f);
    a = fminf(fmaxf(a,0.0f),1.0f);
    aw[t] = a;
    dm[t] = 0.5f*(sD[t]+sD[t+1]);
  } else {
    dm[127] = 0.0f;
  }
  __syncthreads();
  {
    float T = scan_mul_excl(127);
    if (t < 127) vw[t] = aw[t]*T;
    if (t == 127) vw[127] = 0.0f;
  }
  __syncthreads();

  // --- radiance net: layer-1 affine (1 fma/elem), layer-2 via MFMA ---
  // 4 groups x 32 points; wave wv_ does rows [g*32+wv_*16, +16); C: pt=q4*4+r, chan=l15
  float rgbacc = 0.0f;
  for (int g=0; g<4; g++){
    #pragma unroll
    for (int pq=0; pq<8; pq++){
      const float4 dv4 = *(const float4*)&dm[g*32 + pq*4];
      const float dd[4] = {dv4.x, dv4.y, dv4.z, dv4.w};
      #pragma unroll
      for (int r=0;r<4;r++){
        float h = fmaxf(fmaf(dd[r], uR, vR), 0.0f);
        Ah[(pq*4+r)*AS + t] = (_Float16)h;
      }
    }
    __syncthreads();
    half8 ar[4];
    #pragma unroll
    for (int kt=0;kt<4;kt++)
      ar[kt] = *(const half8*)&Ah[(wv_*16 + l15)*AS + kt*32 + q4*8];
    floatx4 racc = (floatx4){0.f,0.f,0.f,0.f};
    #pragma unroll
    for (int kt=0;kt<4;kt++)
      racc = __builtin_amdgcn_mfma_f32_16x16x32_f16(ar[kt], RBf[kt], racc, 0,0,0);
    #pragma unroll
    for (int r=0;r<4;r++){
      int pt = g*32 + wv_*16 + q4*4 + r;
      rgbacc += vw[pt] * sigm(racc[r] + r2lane);
    }
    __syncthreads();
  }

  // --- final reductions: depth, acc (shfl), rgb (quad-fold + cross-wave) ---
  float v3 = (t<127)? vw[t]*dm[t] : 0.f;
  float v4 = (t<127)? vw[t] : 0.f;
  #pragma unroll
  for (int off=32; off>=1; off>>=1){
    v3 += __shfl_xor(v3, off, 64);
    v4 += __shfl_xor(v4, off, 64);
  }
  if ((t&63)==0){ redw[wv_][0]=v3; redw[wv_][1]=v4; }
  rgbacc += __shfl_xor(rgbacc, 16, 64);
  rgbacc += __shfl_xor(rgbacc, 32, 64);
  if ((t&63) < 16 && l15 < 3) rgbw[wv_][l15] = rgbacc;
  __syncthreads();
  if (t==0){
    out[ray*5+0] = rgbw[0][0]+rgbw[1][0];
    out[ray*5+1] = rgbw[0][1]+rgbw[1][1];
    out[ray*5+2] = rgbw[0][2]+rgbw[1][2];
    out[ray*5+3] = redw[0][0]+redw[1][0];
    out[ray*5+4] = redw[0][1]+redw[1][1];
  }
}

extern "C" void kernel_launch(void* const* d_in, const int* in_sizes, int n_in,
                              void* d_out, int out_size, void* d_ws, size_t ws_size,
                              hipStream_t stream) {
  const float* rays_o = (const float*)d_in[0];
  const float* rays_d = (const float*)d_in[1];
  const float* W1 = (const float*)d_in[2];
  const float* b1 = (const float*)d_in[3];
  const float* W2 = (const float*)d_in[4];
  const float* b2 = (const float*)d_in[5];
  const float* W3 = (const float*)d_in[6];
  const float* b3 = (const float*)d_in[7];
  const float* R1 = (const float*)d_in[8];
  const float* r1 = (const float*)d_in[9];
  const float* R2 = (const float*)d_in[10];
  const float* r2 = (const float*)d_in[11];
  const float* sv = (const float*)d_in[12];
  float* out = (float*)d_out;
  neus_render_kernel<<<NRAYS, 128, 0, stream>>>(
      rays_o, rays_d, W1, b1, W2, b2, W3, b3, R1, r1, R2, r2, sv, out);
}

// Round 5
// 188.516 us; speedup vs baseline: 4.8263x; 1.8250x over previous
//
#include <hip/hip_runtime.h>
#include <math.h>

#define NRAYS 8192
#define RPB 8              // rays (= waves) per block
#define AS 136             // Ah row stride in f16 elems (pad vs 128 to spread banks)

typedef _Float16 half8 __attribute__((ext_vector_type(8)));
typedef float floatx4 __attribute__((ext_vector_type(4)));

__device__ __forceinline__ float sigm(float x){ return 1.0f/(1.0f + __expf(-x)); }

// wave-local LDS sync: drain this wave's DS ops; no cross-wave barrier.
__device__ __forceinline__ void wsync(){
  __builtin_amdgcn_wave_barrier();
  __builtin_amdgcn_s_waitcnt(0xc07f);   // lgkmcnt(0) only
  __builtin_amdgcn_wave_barrier();
}

__launch_bounds__(512, 4)
__global__ void neus_render_kernel(
    const float* __restrict__ rays_o, const float* __restrict__ rays_d,
    const float* __restrict__ W1, const float* __restrict__ b1,
    const float* __restrict__ W2, const float* __restrict__ b2,
    const float* __restrict__ W3, const float* __restrict__ b3,
    const float* __restrict__ R1, const float* __restrict__ r1,
    const float* __restrict__ R2, const float* __restrict__ r2,
    const float* __restrict__ s_val, float* __restrict__ out)
{
  // ---- shared: weights (block-shared) + per-ray scratch. Total = 80 KB exactly.
  __shared__ __align__(16) _Float16 W2f[2048*8];     // 32 KB: 32 B-frags x 64 lanes x 8
  __shared__ __align__(16) _Float16 R2f[256*8];      // 4 KB
  __shared__ __align__(16) _Float16 Ah[RPB][16*AS];  // 34 KB: per-ray A staging
  __shared__ __align__(16) float sDm[RPB][128];      // 4 KB
  __shared__ __align__(16) float sSm[RPB][128];      // 4 KB
  __shared__ __align__(16) float fDs[RPB][16];       // 512 B
  __shared__ __align__(16) float fSs[RPB][16];       // 512 B
  __shared__ float b2f[128], w3f[128];               // 1 KB

  const int t = threadIdx.x;

  // ---- cooperative weight staging (only cross-wave cooperation in the kernel)
  #pragma unroll
  for (int r=0;r<4;r++){
    int row = t + r*512;                 // 0..2047: frag-major rows
    int i = row>>8, kt=(row>>6)&3, lr=row&63;
    int q = lr>>4, n = i*16 + (lr&15);
    half8 v;
    #pragma unroll
    for (int j=0;j<8;j++) v[j] = (_Float16)W2[(kt*32+q*8+j)*128 + n];
    *(half8*)&W2f[row*8] = v;
  }
  if (t < 256){
    int kt=t>>6, lr=t&63, q=lr>>4, col=lr&15;
    half8 v;
    #pragma unroll
    for (int j=0;j<8;j++){
      int k = kt*32+q*8+j;
      v[j] = (col<3) ? (_Float16)R2[k*3+col] : (_Float16)0.0f;
    }
    *(half8*)&R2f[t*8] = v;
  }
  if (t < 128){ b2f[t]=b2[t]; w3f[t]=W3[t]; }
  __syncthreads();   // the only block-wide barrier

  const int wv = t>>6, l = t&63, l15 = t&15, q4 = (t>>4)&3;
  const int ray = blockIdx.x*RPB + wv;

  // ---- per-ray data (wave-uniform loads)
  float ro0 = rays_o[ray*3+0], ro1 = rays_o[ray*3+1], ro2 = rays_o[ray*3+2];
  float rx  = rays_d[ray*3+0], ry  = rays_d[ray*3+1], rz  = rays_d[ray*3+2];
  float nrm = sqrtf(rx*rx + ry*ry + rz*rz);
  float rd0 = rx/nrm, rd1 = ry/nrm, rd2 = rz/nrm;
  float sfin = s_val[0] * 64.0f;
  float b3v = b3[0];
  float r2lane = (l15==0) ? r2[0] : (l15==1) ? r2[1] : (l15==2) ? r2[2] : 0.0f;

  // affine-collapsed layer-1: lane owns k0=l and k1=64+l
  float u10, v10, u11, v11, uR0, vR0, uR1, vR1;
  {
    int k=l;
    float a=W1[k], b=W1[128+k], c=W1[256+k];
    u10 = rd0*a+rd1*b+rd2*c; v10 = ro0*a+ro1*b+ro2*c + b1[k];
    float p=R1[k], qq=R1[128+k], s=R1[256+k], d=R1[384+k], e=R1[512+k], f=R1[640+k];
    uR0 = rd0*p+rd1*qq+rd2*s;
    vR0 = ro0*p+ro1*qq+ro2*s + rd0*d+rd1*e+rd2*f + r1[k];
  }
  {
    int k=64+l;
    float a=W1[k], b=W1[128+k], c=W1[256+k];
    u11 = rd0*a+rd1*b+rd2*c; v11 = ro0*a+ro1*b+ro2*c + b1[k];
    float p=R1[k], qq=R1[128+k], s=R1[256+k], d=R1[384+k], e=R1[512+k], f=R1[640+k];
    uR1 = rd0*p+rd1*qq+rd2*s;
    vR1 = ro0*p+ro1*qq+ro2*s + rd0*d+rd1*e+rd2*f + r1[k];
  }

  _Float16* Ahw = &Ah[wv][0];
  float* sD = &sDm[wv][0];
  float* sS = &sSm[wv][0];

  // ---- SDF eval of 16 points, wave-local MFMA (fp16 A, fp16 B from LDS)
  auto eval16 = [&](const float* dptr, float* dstptr){
    const float4* dp4 = (const float4*)dptr;
    float4 dva = dp4[0], dvb = dp4[1], dvc = dp4[2], dvd = dp4[3];
    float dvals[16] = {dva.x,dva.y,dva.z,dva.w, dvb.x,dvb.y,dvb.z,dvb.w,
                       dvc.x,dvc.y,dvc.z,dvc.w, dvd.x,dvd.y,dvd.z,dvd.w};
    #pragma unroll
    for (int m=0;m<16;m++){
      float h0 = fmaxf(fmaf(dvals[m], u10, v10), 0.0f);
      float h1 = fmaxf(fmaf(dvals[m], u11, v11), 0.0f);
      Ahw[m*AS + l]      = (_Float16)h0;
      Ahw[m*AS + 64 + l] = (_Float16)h1;
    }
    wsync();
    half8 A[4];
    #pragma unroll
    for (int kt=0;kt<4;kt++)
      A[kt] = *(const half8*)&Ahw[l15*AS + kt*32 + q4*8];
    floatx4 acc[8];
    #pragma unroll
    for (int i=0;i<8;i++) acc[i] = (floatx4){0.f,0.f,0.f,0.f};
    #pragma unroll
    for (int i=0;i<8;i++){
      #pragma unroll
      for (int kt=0;kt<4;kt++){
        half8 B = *(const half8*)&W2f[((i*4+kt)*64 + l)*8];
        acc[i] = __builtin_amdgcn_mfma_f32_16x16x32_f16(A[kt], B, acc[i], 0,0,0);
      }
    }
    float p0=0.f,p1=0.f,p2=0.f,p3=0.f;
    #pragma unroll
    for (int i=0;i<8;i++){
      float bb = b2f[i*16+l15], ww = w3f[i*16+l15];
      p0 += fmaxf(acc[i][0]+bb,0.0f)*ww;
      p1 += fmaxf(acc[i][1]+bb,0.0f)*ww;
      p2 += fmaxf(acc[i][2]+bb,0.0f)*ww;
      p3 += fmaxf(acc[i][3]+bb,0.0f)*ww;
    }
    #pragma unroll
    for (int off=1; off<16; off<<=1){
      p0 += __shfl_xor(p0, off, 64);
      p1 += __shfl_xor(p1, off, 64);
      p2 += __shfl_xor(p2, off, 64);
      p3 += __shfl_xor(p3, off, 64);
    }
    if (l15==0){
      floatx4 o = {p0+b3v, p1+b3v, p2+b3v, p3+b3v};
      *((floatx4*)&dstptr[q4*4]) = o;
    }
    wsync();
  };

  // ---- initial d: linspace(0.5, 4.0, 64)
  {
    float tt = (float)l / 63.0f;
    sD[l] = 0.5f*(1.0f-tt) + 4.0f*tt;
  }
  wsync();
  for (int c=0;c<4;c++) eval16(&sD[c*16], &sS[c*16]);

  // ---- 4 upsampling iterations (all wave-local; 2 samples/lane: t=l, t=64+l)
  for (int it=0; it<4; it++){
    const int n = 64 + 16*it;
    const int m = n-1;
    const float s_i = 64.0f * (float)(1<<it);

    // load own + neighbor samples
    float dc0 = sD[l],  sc0 = sS[l];
    float dn0 = sD[l+1], snn0 = sS[l+1];
    int lp0 = (l==0)?0:(l-1);
    float dp0 = sD[lp0], sp0 = sS[lp0];
    int i1 = 64+l;
    float dc1 = sD[i1 & 127], sc1 = sS[i1 & 127];
    int i1n = (i1+1) & 127;
    float dn1 = sD[i1n], snn1 = sS[i1n];
    float dp1 = sD[(i1-1) & 127], sp1 = sS[(i1-1) & 127];

    auto alpha_at = [&](float dp, float dc, float dn, float sp, float sc, float sn,
                        bool hasprev)->float{
      float mid = 0.5f*(sc+sn);
      float dv = (sn-sc)/(dn-dc+1e-5f);
      float pdv = hasprev ? (sc-sp)/(dc-dp+1e-5f) : 0.0f;
      float d2 = fminf(fminf(pdv,dv), 0.0f); d2 = fmaxf(d2,-10.0f);
      float dist = dn-dc;
      float pe = mid - d2*dist*0.5f, ne = mid + d2*dist*0.5f;
      float pc = sigm(pe*s_i), nc = sigm(ne*s_i);
      return (pc-nc+1e-5f)/(pc+1e-5f);
    };
    bool va0 = (l < m), va1 = (i1 < m);
    float a0 = va0 ? alpha_at(dp0,dc0,dn0,sp0,sc0,snn0, l>0)  : 0.0f;
    float a1 = va1 ? alpha_at(dp1,dc1,dn1,sp1,sc1,snn1, true) : 0.0f;

    // exclusive cumprod of (1-a+1e-10) over m entries
    float g0 = va0 ? (1.0f-a0+1e-10f) : 1.0f;
    float g1 = va1 ? (1.0f-a1+1e-10f) : 1.0f;
    #pragma unroll
    for (int off=1; off<64; off<<=1){ float y=__shfl_up(g0,off,64); if (l>=off) g0*=y; }
    float gtot0 = __shfl(g0, 63, 64);
    #pragma unroll
    for (int off=1; off<64; off<<=1){ float y=__shfl_up(g1,off,64); if (l>=off) g1*=y; }
    g1 *= gtot0;
    float T0 = __shfl_up(g0, 1, 64); if (l==0) T0 = 1.0f;
    float T1 = __shfl_up(g1, 1, 64); if (l==0) T1 = gtot0;

    // weights + inclusive cumsum
    float w0 = va0 ? (a0*T0 + 1e-5f) : 0.0f;
    float w1 = va1 ? (a1*T1 + 1e-5f) : 0.0f;
    #pragma unroll
    for (int off=1; off<64; off<<=1){ float y=__shfl_up(w0,off,64); if (l>=off) w0+=y; }
    float wtot0 = __shfl(w0, 63, 64);
    #pragma unroll
    for (int off=1; off<64; off<<=1){ float y=__shfl_up(w1,off,64); if (l>=off) w1+=y; }
    w1 += wtot0;
    float S = (m-1 < 64) ? __shfl(w0, m-1, 64) : __shfl(w1, m-65, 64);

    // cdf[t] = t==0 ? 0 : cs[t-1]/S  (length n)
    float csp0 = __shfl_up(w0, 1, 64);
    float cdf0 = (l==0) ? 0.0f : csp0/S;
    float csp1 = __shfl_up(w1, 1, 64);
    float c63  = __shfl(w0, 63, 64);
    float cdf1r = ((l==0) ? c63 : csp1)/S;
    float cdf1m = (i1 < n) ? cdf1r : 2.0f;

    // searchsorted-right for u_q = q/15, q=0..15 (ballot count)
    int ind = 0;
    #pragma unroll
    for (int q=0;q<16;q++){
      float u = (float)q/15.0f;
      unsigned long long bq0 = __ballot(cdf0 <= u);
      unsigned long long bq1 = __ballot(cdf1m <= u);
      int c = __popcll(bq0) + __popcll(bq1);
      if (l==q) ind = c;
    }
    // interp (meaningful on lanes 0..15; others compute garbage harmlessly)
    {
      float u = (float)l15/15.0f;
      int below = ind-1; if (below<0) below=0; if (below>n-1) below=n-1;
      int above = ind;   if (above>n-1) above=n-1;
      float cb = (below<64) ? __shfl(cdf0, below, 64) : __shfl(cdf1r, below-64, 64);
      float ca = (above<64) ? __shfl(cdf0, above, 64) : __shfl(cdf1r, above-64, 64);
      float bb = sD[below], ba = sD[above];
      float den = ca - cb; if (den < 1e-5f) den = 1.0f;
      float tt = (u - cb)/den;
      float fdnew = bb + tt*(ba-bb);
      if (l < 16) fDs[wv][l] = fdnew;
    }
    wsync();

    eval16(&fDs[wv][0], &fSs[wv][0]);

    // stable merge: ranks via compares/ballots, scatter via LDS
    {
      const float4* fp4 = (const float4*)&fDs[wv][0];
      float4 fa = fp4[0], fb = fp4[1], fc = fp4[2], fd = fp4[3];
      float fq[16] = {fa.x,fa.y,fa.z,fa.w, fb.x,fb.y,fb.z,fb.w,
                      fc.x,fc.y,fc.z,fc.w, fd.x,fd.y,fd.z,fd.w};
      float fdv = fDs[wv][l15];
      float fsv = fSs[wv][l15];
      bool v1 = (i1 < n);
      int rold0 = l, rold1 = i1;
      #pragma unroll
      for (int q=0;q<16;q++){
        rold0 += (fq[q] < dc0) ? 1 : 0;
        rold1 += (fq[q] < dc1) ? 1 : 0;
      }
      int rf = 0;
      #pragma unroll
      for (int q=0;q<16;q++){
        unsigned long long bq0 = __ballot(dc0 <= fq[q]);
        unsigned long long bq1 = __ballot(v1 && (dc1 <= fq[q]));
        int c = q + __popcll(bq0) + __popcll(bq1);
        if (l==q) rf = c;
      }
      wsync();
      sD[rold0] = dc0; sS[rold0] = sc0;
      if (v1){ sD[rold1] = dc1; sS[rold1] = sc1; }
      if (l < 16){ sD[rf] = fdv; sS[rf] = fsv; }
      wsync();
    }
  }

  // ---- final compositing (sdf_final == carried sS; n = 128)
  float dm0, dm1, vw0, vw1;
  {
    float d0 = sD[l],  d1 = sD[64+l];
    float s0 = sS[l],  s1 = sS[64+l];
    float dn0 = sD[l+1], sn0 = sS[l+1];
    int i1n = (65+l) & 127;
    float dn1 = sD[i1n], sn1 = sS[i1n];
    bool v1a = (l < 63);                       // t=64+l < 127
    float cf0 = sigm(s0*sfin), cfn0 = sigm(sn0*sfin);
    float a0 = (cf0-cfn0+1e-5f)/(cf0+1e-5f);
    a0 = fminf(fmaxf(a0,0.0f),1.0f);
    float cf1 = sigm(s1*sfin), cfn1 = sigm(sn1*sfin);
    float a1 = (cf1-cfn1+1e-5f)/(cf1+1e-5f);
    a1 = v1a ? fminf(fmaxf(a1,0.0f),1.0f) : 0.0f;
    dm0 = 0.5f*(d0+dn0);
    dm1 = v1a ? 0.5f*(d1+dn1) : 0.0f;

    float g0 = 1.0f-a0+1e-10f;
    float g1 = v1a ? (1.0f-a1+1e-10f) : 1.0f;
    #pragma unroll
    for (int off=1; off<64; off<<=1){ float y=__shfl_up(g0,off,64); if (l>=off) g0*=y; }
    float gtot0 = __shfl(g0, 63, 64);
    #pragma unroll
    for (int off=1; off<64; off<<=1){ float y=__shfl_up(g1,off,64); if (l>=off) g1*=y; }
    g1 *= gtot0;
    float T0 = __shfl_up(g0, 1, 64); if (l==0) T0 = 1.0f;
    float T1 = __shfl_up(g1, 1, 64); if (l==0) T1 = gtot0;
    vw0 = a0*T0;
    vw1 = a1*T1;
    wsync();
    sD[l] = dm0; sD[64+l] = dm1;               // overwrite: sD := d_mid, sS := vis_w
    sS[l] = vw0; sS[64+l] = vw1;
    wsync();
  }

  // ---- radiance net: 8 tiles of 16 points, wave-local MFMA
  half8 RB[4];
  #pragma unroll
  for (int kt=0;kt<4;kt++) RB[kt] = *(const half8*)&R2f[(kt*64+l)*8];
  float rgb = 0.0f;
  for (int g=0; g<8; g++){
    const float4* dp4 = (const float4*)&sDm[wv][g*16];
    float4 dva = dp4[0], dvb = dp4[1], dvc = dp4[2], dvd = dp4[3];
    float dvals[16] = {dva.x,dva.y,dva.z,dva.w, dvb.x,dvb.y,dvb.z,dvb.w,
                       dvc.x,dvc.y,dvc.z,dvc.w, dvd.x,dvd.y,dvd.z,dvd.w};
    #pragma unroll
    for (int m=0;m<16;m++){
      float h0 = fmaxf(fmaf(dvals[m], uR0, vR0), 0.0f);
      float h1 = fmaxf(fmaf(dvals[m], uR1, vR1), 0.0f);
      Ahw[m*AS + l]      = (_Float16)h0;
      Ahw[m*AS + 64 + l] = (_Float16)h1;
    }
    wsync();
    half8 A[4];
    #pragma unroll
    for (int kt=0;kt<4;kt++)
      A[kt] = *(const half8*)&Ahw[l15*AS + kt*32 + q4*8];
    floatx4 racc = (floatx4){0.f,0.f,0.f,0.f};
    #pragma unroll
    for (int kt=0;kt<4;kt++)
      racc = __builtin_amdgcn_mfma_f32_16x16x32_f16(A[kt], RB[kt], racc, 0,0,0);
    #pragma unroll
    for (int r=0;r<4;r++){
      int pt = g*16 + q4*4 + r;
      float w = sS[pt];
      rgb += w * sigm(racc[r] + r2lane);
    }
    wsync();
  }

  // ---- reductions + output
  float v3 = dm0*vw0 + dm1*vw1;
  float v4 = vw0 + vw1;
  #pragma unroll
  for (int off=32; off>=1; off>>=1){
    v3 += __shfl_xor(v3, off, 64);
    v4 += __shfl_xor(v4, off, 64);
  }
  rgb += __shfl_xor(rgb, 16, 64);
  rgb += __shfl_xor(rgb, 32, 64);
  if (l < 3)  out[ray*5 + l] = rgb;
  if (l == 3) out[ray*5 + 3] = v3;
  if (l == 4) out[ray*5 + 4] = v4;
}

extern "C" void kernel_launch(void* const* d_in, const int* in_sizes, int n_in,
                              void* d_out, int out_size, void* d_ws, size_t ws_size,
                              hipStream_t stream) {
  const float* rays_o = (const float*)d_in[0];
  const float* rays_d = (const float*)d_in[1];
  const float* W1 = (const float*)d_in[2];
  const float* b1 = (const float*)d_in[3];
  const float* W2 = (const float*)d_in[4];
  const float* b2 = (const float*)d_in[5];
  const float* W3 = (const float*)d_in[6];
  const float* b3 = (const float*)d_in[7];
  const float* R1 = (const float*)d_in[8];
  const float* r1 = (const float*)d_in[9];
  const float* R2 = (const float*)d_in[10];
  const float* r2 = (const float*)d_in[11];
  const float* sv = (const float*)d_in[12];
  float* out = (float*)d_out;
  neus_render_kernel<<<NRAYS/RPB, 512, 0, stream>>>(
      rays_o, rays_d, W1, b1, W2, b2, W3, b3, R1, r1, R2, r2, sv, out);
}